// Round 12
// baseline (520.239 us; speedup 1.0000x reference)
//
#include <hip/hip_runtime.h>
#include <hip/hip_bf16.h>
#include <stddef.h>

#define HH 96
#define WW 96
#define NPIX 9216
#define LBL 21
#define LPAD 32
#define RAD 9            // int(3 * POS_STD)
#define N_ITER 10
#define POS_W_C 3.0f
#define BI_W_C 10.0f
#define INV_XY (1.0f/80.0f)
#define INV_RGB (1.0f/13.0f)

// bilateral GEMM blocking
#define JCH 16                       // j chunks (block dimension)
#define JC (NPIX / JCH)              // 576 columns per chunk
#define JTOT (NPIX / 32)             // 288 jt-tiles (swizzled layouts)
#define ITILE 128                    // rows per block (4 waves x 2 subtiles x 16)
#define NITB (NPIX / ITILE)          // 72 i-blocks
#define NSPB (LBL * 24)              // 504 conv bands (4 rows each)
#define KSPLIT 8                     // k_K j-split factor
#define PSTR 24                      // P inner stride (floats)
#define QHALF (JTOT * 64 * 8)        // 147456 ushorts per Qt half-buffer

typedef __bf16 bf16x8 __attribute__((ext_vector_type(8)));
typedef float  f32x4  __attribute__((ext_vector_type(4)));

// exp(-0.5*(d/3)^2), d = -9..9  (matches reference _gauss1d(3.0))
__device__ const float GK[2 * RAD + 1] = {
    0.01110900f, 0.02856548f, 0.06572886f, 0.13533528f, 0.24935220f,
    0.41111229f, 0.60653066f, 0.80073740f, 0.94595947f, 1.00000000f,
    0.94595947f, 0.80073740f, 0.60653066f, 0.41111229f, 0.24935220f,
    0.13533528f, 0.06572886f, 0.02856548f, 0.01110900f
};

__device__ __forceinline__ unsigned short f2bf(float f) {
    unsigned u = __float_as_uint(f);
    unsigned r = (u + 0x7fffu + ((u >> 16) & 1u)) >> 16;
    return (unsigned short)r;
}
__device__ __forceinline__ float bf2f(unsigned short s) {
    return __uint_as_float(((unsigned)s) << 16);
}
__device__ __forceinline__ unsigned pk2bf(float a, float b) {
    __hip_bfloat162 h = __float22bfloat162_rn(make_float2(a, b));
    return *(unsigned*)&h;
}
// swizzled Qt element index for (pixel p, label l)
__device__ __forceinline__ size_t qtidx(int p, int l) {
    size_t half = (l >> 4) ? (size_t)QHALF : 0;
    return half + ((((p >> 5) * 64 + ((p >> 3) & 3) * 16 + (l & 15)) << 3) + (p & 7));
}

// ---------------------------------------------------------------- k_prep
__global__ void k_prep(const float* __restrict__ I,
                       float* __restrict__ fx, float* __restrict__ fy,
                       float* __restrict__ fr, float* __restrict__ fg,
                       float* __restrict__ fb, float* __restrict__ S,
                       float* __restrict__ nsp) {
    int n = blockIdx.x * 256 + threadIdx.x;
    if (n >= NPIX) return;
    int y = n / WW, x = n % WW;
    float vx = (float)x * INV_XY;
    float vy = (float)y * INV_XY;
    float vr = I[n] * INV_RGB;
    float vg = I[NPIX + n] * INV_RGB;
    float vb = I[2 * NPIX + n] * INV_RGB;
    fx[n] = vx; fy[n] = vy; fr[n] = vr; fg[n] = vg; fb[n] = vb;
    S[n] = -0.5f * (vx*vx + vy*vy + vr*vr + vg*vg + vb*vb);
    float sy = 0.f, sx = 0.f;
    #pragma unroll
    for (int d = -RAD; d <= RAD; ++d) {
        float g = GK[d + RAD];
        if ((unsigned)(y + d) < HH) sy += g;
        if ((unsigned)(x + d) < WW) sx += g;
    }
    nsp[n] = rsqrtf(sy * sx);
}

// ---------------------------------------------------------------- k_K
// grid = (NPIX/16) * KSPLIT. Block (it, part): 16 i-rows, 36 jtiles.
// Thread owns slot (tid&63) of jtile pass*4+(tid>>6): 8 consecutive j,
// one uint4 store -> 4KB contiguous per pass.
template <bool STORE>
__global__ void __launch_bounds__(256)
k_K(const float* __restrict__ fx, const float* __restrict__ fy,
    const float* __restrict__ fr, const float* __restrict__ fg,
    const float* __restrict__ fb, const float* __restrict__ S,
    float* __restrict__ RS, unsigned short* __restrict__ K) {
    int it = blockIdx.x >> 3;
    int part = blockIdx.x & 7;
    int tid = threadIdx.x;
    int m = tid & 15;
    int g = tid >> 4;        // ts*4 + khs
    int khs = g & 3;
    int ts = g >> 2;
    int i = it * 16 + m;
    float hx = fx[i], hy = fy[i], hr = fr[i], hg = fg[i], hb = fb[i];
    float ci = S[i];
    unsigned short* Kb = K + (size_t)it * JTOT * 512;
    float sum = 0.f;
    for (int pass = 0; pass < JTOT / (4 * KSPLIT); ++pass) {   // 9 passes
        int jtile = part * (JTOT / KSPLIT) + pass * 4 + ts;
        int j = jtile * 32 + khs * 8;
        float4 x0 = *(const float4*)(fx + j), x1 = *(const float4*)(fx + j + 4);
        float4 y0 = *(const float4*)(fy + j), y1 = *(const float4*)(fy + j + 4);
        float4 r0 = *(const float4*)(fr + j), r1 = *(const float4*)(fr + j + 4);
        float4 g0 = *(const float4*)(fg + j), g1 = *(const float4*)(fg + j + 4);
        float4 b0 = *(const float4*)(fb + j), b1 = *(const float4*)(fb + j + 4);
        float4 s0 = *(const float4*)(S + j),  s1 = *(const float4*)(S + j + 4);
        float k0 = __expf(ci + s0.x + hx*x0.x + hy*y0.x + hr*r0.x + hg*g0.x + hb*b0.x);
        float k1 = __expf(ci + s0.y + hx*x0.y + hy*y0.y + hr*r0.y + hg*g0.y + hb*b0.y);
        float k2 = __expf(ci + s0.z + hx*x0.z + hy*y0.z + hr*r0.z + hg*g0.z + hb*b0.z);
        float k3 = __expf(ci + s0.w + hx*x0.w + hy*y0.w + hr*r0.w + hg*g0.w + hb*b0.w);
        float k4 = __expf(ci + s1.x + hx*x1.x + hy*y1.x + hr*r1.x + hg*g1.x + hb*b1.x);
        float k5 = __expf(ci + s1.y + hx*x1.y + hy*y1.y + hr*r1.y + hg*g1.y + hb*b1.y);
        float k6 = __expf(ci + s1.z + hx*x1.z + hy*y1.z + hr*r1.z + hg*g1.z + hb*b1.z);
        float k7 = __expf(ci + s1.w + hx*x1.w + hy*y1.w + hr*r1.w + hg*g1.w + hb*b1.w);
        sum += ((k0 + k1) + (k2 + k3)) + ((k4 + k5) + (k6 + k7));
        if (STORE) {
            uint4 u;
            u.x = pk2bf(k0, k1);
            u.y = pk2bf(k2, k3);
            u.z = pk2bf(k4, k5);
            u.w = pk2bf(k6, k7);
            *(uint4*)(Kb + (size_t)jtile * 512 + (tid & 63) * 8) = u;
        }
    }
    __shared__ float red[16][17];
    red[g][m] = sum;
    __syncthreads();
    if (tid < 16) {
        float tot = 0.f;
        #pragma unroll
        for (int q = 0; q < 16; ++q) tot += red[q][tid];
        RS[part * NPIX + it * 16 + tid] = tot;
    }
}

// ---------------------------------------------------------------- k_q0
// folds RS partials into nbi, softmax(-U), emits A + swizzled Qt
__global__ void k_q0(const float* __restrict__ U, const float* __restrict__ RS,
                     const float* __restrict__ nsp,
                     float* __restrict__ nbi, float* __restrict__ A,
                     unsigned short* __restrict__ Qt0, unsigned short* __restrict__ Qt1) {
    int n = blockIdx.x * 256 + threadIdx.x;
    if (n >= NPIX) return;
    float rs = 0.f;
    #pragma unroll
    for (int q = 0; q < KSPLIT; ++q) rs += RS[q * NPIX + n];
    float nb = rsqrtf(rs);
    nbi[n] = nb;
    float v[LBL];
    float mx = -1e30f;
    #pragma unroll
    for (int l = 0; l < LBL; ++l) { v[l] = -U[l * NPIX + n]; mx = fmaxf(mx, v[l]); }
    float s = 0.f;
    #pragma unroll
    for (int l = 0; l < LBL; ++l) { v[l] = __expf(v[l] - mx); s += v[l]; }
    float inv = 1.f / s;
    float ns = nsp[n];
    #pragma unroll
    for (int l = 0; l < LBL; ++l) {
        float q = v[l] * inv;
        A[l * NPIX + n] = ns * q;
        Qt0[qtidx(n, l)] = f2bf(nb * q);
    }
    #pragma unroll
    for (int l = LBL; l < LPAD; ++l) {
        Qt0[qtidx(n, l)] = 0;
        Qt1[qtidx(n, l)] = 0;
    }
}

// ---------------------------------------------------------------- k_sp (slow path)
__global__ void k_sp(const float* __restrict__ A, const float* __restrict__ nsp,
                     const float* __restrict__ U, float* __restrict__ SP) {
    __shared__ float ty[4 * WW];
    int l = blockIdx.x / 24;
    int y0 = (blockIdx.x % 24) * 4;
    int t = threadIdx.x;
    const float* Al = A + (size_t)l * NPIX;
    #pragma unroll
    for (int c = 0; c < 2; ++c) {
        int p = t + c * 256;
        if (p < 4 * WW) {
            int yy = p / WW, x = p % WW;
            int y = y0 + yy;
            float s = 0.f;
            #pragma unroll
            for (int d = -RAD; d <= RAD; ++d) {
                int yd = y + d;
                if ((unsigned)yd < HH) s += GK[d + RAD] * Al[yd * WW + x];
            }
            ty[p] = s;
        }
    }
    __syncthreads();
    #pragma unroll
    for (int c = 0; c < 2; ++c) {
        int p = t + c * 256;
        if (p < 4 * WW) {
            int yy = p / WW, x = p % WW;
            float s = 0.f;
            #pragma unroll
            for (int d = -RAD; d <= RAD; ++d) {
                int xd = x + d;
                if ((unsigned)xd < WW) s += GK[d + RAD] * ty[yy * WW + xd];
            }
            int pp = (y0 + yy) * WW + x;
            SP[(size_t)l * NPIX + pp] = POS_W_C * nsp[pp] * s - U[(size_t)l * NPIX + pp];
        }
    }
}

// ---------------------------------------------------------------- k_bi_fast
// grid = NITB*JCH = 1152, LDS-free GEMM. Blocks 0..503 first run one
// spatial-conv band. Each wave: TWO 16-row i-tiles (64 apart) sharing B
// fragments, 18 jt tiles, explicit A-prefetch rotation. launch_bounds(256,4)
// -> 128 VGPR so the A stream keeps 4+ loads in flight.
__global__ void __launch_bounds__(256, 4)
k_bi_fast(const unsigned short* __restrict__ K, const unsigned short* __restrict__ Qt,
          const float* __restrict__ A, const float* __restrict__ nsp,
          const float* __restrict__ U, float* __restrict__ SP,
          float* __restrict__ P) {
    int tid = threadIdx.x;
    int bid = blockIdx.x;

    // ---- fused spatial conv band (blocks 0..503)
    __shared__ float ty[4 * WW];
    if (bid < NSPB) {
        int l = bid / 24;
        int y0b = (bid % 24) * 4;
        const float* Al = A + (size_t)l * NPIX;
        #pragma unroll
        for (int c = 0; c < 2; ++c) {
            int p = tid + c * 256;
            if (p < 4 * WW) {
                int yy = p / WW, x = p % WW;
                int y = y0b + yy;
                float s = 0.f;
                #pragma unroll
                for (int d = -RAD; d <= RAD; ++d) {
                    int yd = y + d;
                    if ((unsigned)yd < HH) s += GK[d + RAD] * Al[yd * WW + x];
                }
                ty[p] = s;
            }
        }
        __syncthreads();
        #pragma unroll
        for (int c = 0; c < 2; ++c) {
            int p = tid + c * 256;
            if (p < 4 * WW) {
                int yy = p / WW, x = p % WW;
                float s = 0.f;
                #pragma unroll
                for (int d = -RAD; d <= RAD; ++d) {
                    int xd = x + d;
                    if ((unsigned)xd < WW) s += GK[d + RAD] * ty[yy * WW + xd];
                }
                int pp = (y0b + yy) * WW + x;
                SP[(size_t)l * NPIX + pp] = POS_W_C * nsp[pp] * s - U[(size_t)l * NPIX + pp];
            }
        }
    }

    int jc  = bid / NITB;          // 0..15
    int itb = bid % NITB;          // 0..71
    int jtb = jc * (JC / 32);      // 18 jtiles per chunk

    int lane = tid & 63;
    int wv = tid >> 6;
    int m  = lane & 15;
    int kh = lane >> 4;

    const bf16x8* pa0 = (const bf16x8*)K + ((size_t)(itb * 8 + wv)     * JTOT + jtb) * 64 + lane;
    const bf16x8* pa1 = (const bf16x8*)K + ((size_t)(itb * 8 + 4 + wv) * JTOT + jtb) * 64 + lane;
    const bf16x8* pb0 = (const bf16x8*)Qt + (size_t)jtb * 64 + lane;
    const bf16x8* pb1 = (const bf16x8*)Qt + (size_t)(QHALF / 8) + (size_t)jtb * 64 + lane;

    f32x4 acc00 = {0.f,0.f,0.f,0.f}, acc01 = {0.f,0.f,0.f,0.f};
    f32x4 acc10 = {0.f,0.f,0.f,0.f}, acc11 = {0.f,0.f,0.f,0.f};

    bf16x8 a0c = pa0[0];
    bf16x8 a1c = pa1[0];
    #pragma unroll
    for (int jt = 0; jt < JC / 32 - 1; ++jt) {     // 17 iters + peeled last
        bf16x8 a0n = pa0[(jt + 1) * 64];
        bf16x8 a1n = pa1[(jt + 1) * 64];
        bf16x8 b0 = pb0[jt * 64];
        bf16x8 b1 = pb1[jt * 64];
        acc00 = __builtin_amdgcn_mfma_f32_16x16x32_bf16(a0c, b0, acc00, 0, 0, 0);
        acc01 = __builtin_amdgcn_mfma_f32_16x16x32_bf16(a0c, b1, acc01, 0, 0, 0);
        acc10 = __builtin_amdgcn_mfma_f32_16x16x32_bf16(a1c, b0, acc10, 0, 0, 0);
        acc11 = __builtin_amdgcn_mfma_f32_16x16x32_bf16(a1c, b1, acc11, 0, 0, 0);
        a0c = a0n; a1c = a1n;
    }
    {
        int jt = JC / 32 - 1;
        bf16x8 b0 = pb0[jt * 64];
        bf16x8 b1 = pb1[jt * 64];
        acc00 = __builtin_amdgcn_mfma_f32_16x16x32_bf16(a0c, b0, acc00, 0, 0, 0);
        acc01 = __builtin_amdgcn_mfma_f32_16x16x32_bf16(a0c, b1, acc01, 0, 0, 0);
        acc10 = __builtin_amdgcn_mfma_f32_16x16x32_bf16(a1c, b0, acc10, 0, 0, 0);
        acc11 = __builtin_amdgcn_mfma_f32_16x16x32_bf16(a1c, b1, acc11, 0, 0, 0);
    }

    // partials; C/D layout col(label)=m, row=kh*4+r
    float* Pp = P + (size_t)jc * NPIX * PSTR;
    int i0 = itb * 128 + wv * 16 + kh * 4;
    int i1 = i0 + 64;
    #pragma unroll
    for (int r = 0; r < 4; ++r) {
        Pp[(size_t)(i0 + r) * PSTR + m] = acc00[r];
        Pp[(size_t)(i1 + r) * PSTR + m] = acc10[r];
        if (m < 8) {
            Pp[(size_t)(i0 + r) * PSTR + 16 + m] = acc01[r];
            Pp[(size_t)(i1 + r) * PSTR + 16 + m] = acc11[r];
        }
    }
}

// ---------------------------------------------------------------- k_red
// 288 blocks x 256: 8 groups each sum 2 j-chunks; LDS reduce (stride-25 pad);
// wave-0 lanes do fused softmax epilogue + swizzled Qt writes.
__global__ void __launch_bounds__(256)
k_red(const float* __restrict__ P, const float* __restrict__ SP,
      const float* __restrict__ nbi, const float* __restrict__ nsp,
      float* __restrict__ Qo, float* __restrict__ Ao,
      unsigned short* __restrict__ Qto) {
    __shared__ float red[8][32][25];
    int tid = threadIdx.x;
    int p32 = tid & 31;
    int g = tid >> 5;
    int p = blockIdx.x * 32 + p32;

    float4 s[6] = {{0,0,0,0},{0,0,0,0},{0,0,0,0},{0,0,0,0},{0,0,0,0},{0,0,0,0}};
    #pragma unroll
    for (int jj = 0; jj < 2; ++jj) {
        int jcc = g * 2 + jj;
        const float4* pp = (const float4*)(P + ((size_t)jcc * NPIX + p) * PSTR);
        #pragma unroll
        for (int q = 0; q < 6; ++q) s[q] += pp[q];
    }
    #pragma unroll
    for (int q = 0; q < 6; ++q) {
        red[g][p32][4*q+0] = s[q].x;
        red[g][p32][4*q+1] = s[q].y;
        red[g][p32][4*q+2] = s[q].z;
        red[g][p32][4*q+3] = s[q].w;
    }
    __syncthreads();
    if (tid >= 32) return;

    float nb = nbi[p];
    float ns = nsp[p];
    float v[LBL];
    float mx = -1e30f;
    #pragma unroll
    for (int l = 0; l < LBL; ++l) {
        float bi = 0.f;
        #pragma unroll
        for (int q = 0; q < 8; ++q) bi += red[q][p32][l];
        v[l] = SP[l * NPIX + p] + BI_W_C * nb * bi;
        mx = fmaxf(mx, v[l]);
    }
    float ssum = 0.f;
    #pragma unroll
    for (int l = 0; l < LBL; ++l) { v[l] = __expf(v[l] - mx); ssum += v[l]; }
    float inv = 1.f / ssum;
    #pragma unroll
    for (int l = 0; l < LBL; ++l) {
        float q = v[l] * inv;
        Qo[l * NPIX + p] = q;
        Ao[l * NPIX + p] = ns * q;
        Qto[qtidx(p, l)] = f2bf(nb * q);
    }
}

// ---------------------------------------------------------------- k_bi_slow
__global__ void k_bi_slow(const float* __restrict__ fx, const float* __restrict__ fy,
                          const float* __restrict__ fr, const float* __restrict__ fg,
                          const float* __restrict__ fb,
                          const float* __restrict__ nbi, const unsigned short* __restrict__ Qt,
                          const float* __restrict__ SP, const float* __restrict__ nsp,
                          float* __restrict__ Qo, float* __restrict__ Ao,
                          unsigned short* __restrict__ Qto) {
    int t = threadIdx.x;
    int px = t & 15, st = t >> 4;
    int i = blockIdx.x * 16 + px;
    float xi = fx[i], yi = fy[i], ri = fr[i], gi = fg[i], bi = fb[i];
    float acc[LBL];
    #pragma unroll
    for (int l = 0; l < LBL; ++l) acc[l] = 0.f;
    int j0 = st * (NPIX / 16);
    for (int j = j0; j < j0 + NPIX / 16; ++j) {
        float dx = xi - fx[j], dy = yi - fy[j];
        float dr = ri - fr[j], dg = gi - fg[j], db = bi - fb[j];
        float D = dx*dx + dy*dy + dr*dr + dg*dg + db*db;
        float w = __expf(-0.5f * D);
        #pragma unroll
        for (int l = 0; l < LBL; ++l) acc[l] += w * bf2f(Qt[qtidx(j, l)]);
    }
    __shared__ float red[16][LBL];
    if (st == 0) {
        #pragma unroll
        for (int l = 0; l < LBL; ++l) red[px][l] = acc[l];
    }
    __syncthreads();
    for (int s = 1; s < 16; ++s) {
        if (st == s) {
            #pragma unroll
            for (int l = 0; l < LBL; ++l) red[px][l] += acc[l];
        }
        __syncthreads();
    }
    if (t < 16) {
        int i2 = blockIdx.x * 16 + t;
        float nb = nbi[i2];
        float ns = nsp[i2];
        float v[LBL];
        float mx = -1e30f;
        #pragma unroll
        for (int l = 0; l < LBL; ++l) {
            v[l] = SP[l * NPIX + i2] + BI_W_C * nb * red[t][l];
            mx = fmaxf(mx, v[l]);
        }
        float s = 0.f;
        #pragma unroll
        for (int l = 0; l < LBL; ++l) { v[l] = __expf(v[l] - mx); s += v[l]; }
        float inv = 1.f / s;
        #pragma unroll
        for (int l = 0; l < LBL; ++l) {
            float q = v[l] * inv;
            Qo[l * NPIX + i2] = q;
            Ao[l * NPIX + i2] = ns * q;
            Qto[qtidx(i2, l)] = f2bf(nb * q);
        }
    }
}

// ---------------------------------------------------------------- launch
extern "C" void kernel_launch(void* const* d_in, const int* in_sizes, int n_in,
                              void* d_out, int out_size, void* d_ws, size_t ws_size,
                              hipStream_t stream) {
    const float* U = (const float*)d_in[0];
    const float* I = (const float*)d_in[1];

    char* w = (char*)d_ws;
    float* fx  = (float*)w;                 w += NPIX * sizeof(float);
    float* fy  = (float*)w;                 w += NPIX * sizeof(float);
    float* fr  = (float*)w;                 w += NPIX * sizeof(float);
    float* fg  = (float*)w;                 w += NPIX * sizeof(float);
    float* fb  = (float*)w;                 w += NPIX * sizeof(float);
    float* S   = (float*)w;                 w += NPIX * sizeof(float);
    float* nsp = (float*)w;                 w += NPIX * sizeof(float);
    float* nbi = (float*)w;                 w += NPIX * sizeof(float);
    float* RS  = (float*)w;                 w += (size_t)KSPLIT * NPIX * sizeof(float);
    float* A   = (float*)w;                 w += (size_t)LBL * NPIX * sizeof(float);
    float* SP  = (float*)w;                 w += (size_t)LBL * NPIX * sizeof(float);
    unsigned short* Qtb[2];
    Qtb[0] = (unsigned short*)w;            w += (size_t)2 * QHALF * sizeof(unsigned short);
    Qtb[1] = (unsigned short*)w;            w += (size_t)2 * QHALF * sizeof(unsigned short);
    float* P = (float*)w;                   w += (size_t)JCH * NPIX * PSTR * sizeof(float);
    unsigned short* K = (unsigned short*)w;
    size_t need = (size_t)(w - (char*)d_ws) + (size_t)NPIX * NPIX * sizeof(unsigned short);
    bool fast = (ws_size >= need);

    float* Qout = (float*)d_out;

    k_prep<<<(NPIX + 255) / 256, 256, 0, stream>>>(I, fx, fy, fr, fg, fb, S, nsp);
    if (fast) k_K<true ><<<(NPIX / 16) * KSPLIT, 256, 0, stream>>>(fx, fy, fr, fg, fb, S, RS, K);
    else      k_K<false><<<(NPIX / 16) * KSPLIT, 256, 0, stream>>>(fx, fy, fr, fg, fb, S, RS, nullptr);
    k_q0<<<(NPIX + 255) / 256, 256, 0, stream>>>(U, RS, nsp, nbi, A, Qtb[0], Qtb[1]);

    for (int t = 0; t < N_ITER; ++t) {
        const unsigned short* Qtin = Qtb[t & 1];
        unsigned short* Qtout = Qtb[(t + 1) & 1];
        if (fast) {
            k_bi_fast<<<NITB * JCH, 256, 0, stream>>>(K, Qtin, A, nsp, U, SP, P);
            k_red<<<NPIX / 32, 256, 0, stream>>>(P, SP, nbi, nsp, Qout, A, Qtout);
        } else {
            k_sp<<<NSPB, 256, 0, stream>>>(A, nsp, U, SP);
            k_bi_slow<<<NPIX / 16, 256, 0, stream>>>(fx, fy, fr, fg, fb, nbi, Qtin, SP, nsp, Qout, A, Qtout);
        }
    }
}

// Round 13
// 490.525 us; speedup vs baseline: 1.0606x; 1.0606x over previous
//
#include <hip/hip_runtime.h>
#include <hip/hip_bf16.h>
#include <stddef.h>

#define HH 96
#define WW 96
#define NPIX 9216
#define LBL 21
#define LPAD 32
#define RAD 9            // int(3 * POS_STD)
#define N_ITER 10
#define POS_W_C 3.0f
#define BI_W_C 10.0f
#define INV_XY (1.0f/80.0f)
#define INV_RGB (1.0f/13.0f)

// bilateral GEMM blocking (round-8 config: best measured 509 us)
#define JCH 16                       // j chunks (block dimension)
#define JC (NPIX / JCH)              // 576 columns per chunk
#define JTOT (NPIX / 32)             // 288 jt-tiles (swizzled layouts)
#define ITILE 64                     // rows per block (4 waves x 16)
#define NITB (NPIX / ITILE)          // 144 i-blocks
#define NSPB (LBL * 24)              // 504 conv bands (4 rows each)
#define KSPLIT 8                     // k_K j-split factor
#define PSTR 24                      // P inner stride (bf16 elements)
#define QHALF (JTOT * 64 * 8)        // 147456 ushorts per Qt half-buffer

typedef __bf16 bf16x8 __attribute__((ext_vector_type(8)));
typedef float  f32x4  __attribute__((ext_vector_type(4)));

// exp(-0.5*(d/3)^2), d = -9..9  (matches reference _gauss1d(3.0))
__device__ const float GK[2 * RAD + 1] = {
    0.01110900f, 0.02856548f, 0.06572886f, 0.13533528f, 0.24935220f,
    0.41111229f, 0.60653066f, 0.80073740f, 0.94595947f, 1.00000000f,
    0.94595947f, 0.80073740f, 0.60653066f, 0.41111229f, 0.24935220f,
    0.13533528f, 0.06572886f, 0.02856548f, 0.01110900f
};

__device__ __forceinline__ unsigned short f2bf(float f) {
    unsigned u = __float_as_uint(f);
    unsigned r = (u + 0x7fffu + ((u >> 16) & 1u)) >> 16;
    return (unsigned short)r;
}
__device__ __forceinline__ float bf2f(unsigned short s) {
    return __uint_as_float(((unsigned)s) << 16);
}
__device__ __forceinline__ unsigned pk2bf(float a, float b) {
    __hip_bfloat162 h = __float22bfloat162_rn(make_float2(a, b));
    return *(unsigned*)&h;
}
// swizzled Qt element index for (pixel p, label l)
__device__ __forceinline__ size_t qtidx(int p, int l) {
    size_t half = (l >> 4) ? (size_t)QHALF : 0;
    return half + ((((p >> 5) * 64 + ((p >> 3) & 3) * 16 + (l & 15)) << 3) + (p & 7));
}

// ---------------------------------------------------------------- k_prep
__global__ void k_prep(const float* __restrict__ I,
                       float* __restrict__ fx, float* __restrict__ fy,
                       float* __restrict__ fr, float* __restrict__ fg,
                       float* __restrict__ fb, float* __restrict__ S,
                       float* __restrict__ nsp) {
    int n = blockIdx.x * 256 + threadIdx.x;
    if (n >= NPIX) return;
    int y = n / WW, x = n % WW;
    float vx = (float)x * INV_XY;
    float vy = (float)y * INV_XY;
    float vr = I[n] * INV_RGB;
    float vg = I[NPIX + n] * INV_RGB;
    float vb = I[2 * NPIX + n] * INV_RGB;
    fx[n] = vx; fy[n] = vy; fr[n] = vr; fg[n] = vg; fb[n] = vb;
    S[n] = -0.5f * (vx*vx + vy*vy + vr*vr + vg*vg + vb*vb);
    float sy = 0.f, sx = 0.f;
    #pragma unroll
    for (int d = -RAD; d <= RAD; ++d) {
        float g = GK[d + RAD];
        if ((unsigned)(y + d) < HH) sy += g;
        if ((unsigned)(x + d) < WW) sx += g;
    }
    nsp[n] = rsqrtf(sy * sx);
}

// ---------------------------------------------------------------- k_K
// grid = (NPIX/16) * KSPLIT. Block (it, part): 16 i-rows, 36 jtiles.
// Thread owns slot (tid&63) of jtile pass*4+(tid>>6): 8 consecutive j,
// one uint4 store -> 4KB contiguous per pass.
template <bool STORE>
__global__ void __launch_bounds__(256)
k_K(const float* __restrict__ fx, const float* __restrict__ fy,
    const float* __restrict__ fr, const float* __restrict__ fg,
    const float* __restrict__ fb, const float* __restrict__ S,
    float* __restrict__ RS, unsigned short* __restrict__ K) {
    int it = blockIdx.x >> 3;
    int part = blockIdx.x & 7;
    int tid = threadIdx.x;
    int m = tid & 15;
    int g = tid >> 4;        // ts*4 + khs
    int khs = g & 3;
    int ts = g >> 2;
    int i = it * 16 + m;
    float hx = fx[i], hy = fy[i], hr = fr[i], hg = fg[i], hb = fb[i];
    float ci = S[i];
    unsigned short* Kb = K + (size_t)it * JTOT * 512;
    float sum = 0.f;
    for (int pass = 0; pass < JTOT / (4 * KSPLIT); ++pass) {   // 9 passes
        int jtile = part * (JTOT / KSPLIT) + pass * 4 + ts;
        int j = jtile * 32 + khs * 8;
        float4 x0 = *(const float4*)(fx + j), x1 = *(const float4*)(fx + j + 4);
        float4 y0 = *(const float4*)(fy + j), y1 = *(const float4*)(fy + j + 4);
        float4 r0 = *(const float4*)(fr + j), r1 = *(const float4*)(fr + j + 4);
        float4 g0 = *(const float4*)(fg + j), g1 = *(const float4*)(fg + j + 4);
        float4 b0 = *(const float4*)(fb + j), b1 = *(const float4*)(fb + j + 4);
        float4 s0 = *(const float4*)(S + j),  s1 = *(const float4*)(S + j + 4);
        float k0 = __expf(ci + s0.x + hx*x0.x + hy*y0.x + hr*r0.x + hg*g0.x + hb*b0.x);
        float k1 = __expf(ci + s0.y + hx*x0.y + hy*y0.y + hr*r0.y + hg*g0.y + hb*b0.y);
        float k2 = __expf(ci + s0.z + hx*x0.z + hy*y0.z + hr*r0.z + hg*g0.z + hb*b0.z);
        float k3 = __expf(ci + s0.w + hx*x0.w + hy*y0.w + hr*r0.w + hg*g0.w + hb*b0.w);
        float k4 = __expf(ci + s1.x + hx*x1.x + hy*y1.x + hr*r1.x + hg*g1.x + hb*b1.x);
        float k5 = __expf(ci + s1.y + hx*x1.y + hy*y1.y + hr*r1.y + hg*g1.y + hb*b1.y);
        float k6 = __expf(ci + s1.z + hx*x1.z + hy*y1.z + hr*r1.z + hg*g1.z + hb*b1.z);
        float k7 = __expf(ci + s1.w + hx*x1.w + hy*y1.w + hr*r1.w + hg*g1.w + hb*b1.w);
        sum += ((k0 + k1) + (k2 + k3)) + ((k4 + k5) + (k6 + k7));
        if (STORE) {
            uint4 u;
            u.x = pk2bf(k0, k1);
            u.y = pk2bf(k2, k3);
            u.z = pk2bf(k4, k5);
            u.w = pk2bf(k6, k7);
            *(uint4*)(Kb + (size_t)jtile * 512 + (tid & 63) * 8) = u;
        }
    }
    __shared__ float red[16][17];
    red[g][m] = sum;
    __syncthreads();
    if (tid < 16) {
        float tot = 0.f;
        #pragma unroll
        for (int q = 0; q < 16; ++q) tot += red[q][tid];
        RS[part * NPIX + it * 16 + tid] = tot;
    }
}

// ---------------------------------------------------------------- k_q0
// folds RS partials into nbi, softmax(-U), emits A + swizzled Qt
__global__ void k_q0(const float* __restrict__ U, const float* __restrict__ RS,
                     const float* __restrict__ nsp,
                     float* __restrict__ nbi, float* __restrict__ A,
                     unsigned short* __restrict__ Qt0, unsigned short* __restrict__ Qt1) {
    int n = blockIdx.x * 256 + threadIdx.x;
    if (n >= NPIX) return;
    float rs = 0.f;
    #pragma unroll
    for (int q = 0; q < KSPLIT; ++q) rs += RS[q * NPIX + n];
    float nb = rsqrtf(rs);
    nbi[n] = nb;
    float v[LBL];
    float mx = -1e30f;
    #pragma unroll
    for (int l = 0; l < LBL; ++l) { v[l] = -U[l * NPIX + n]; mx = fmaxf(mx, v[l]); }
    float s = 0.f;
    #pragma unroll
    for (int l = 0; l < LBL; ++l) { v[l] = __expf(v[l] - mx); s += v[l]; }
    float inv = 1.f / s;
    float ns = nsp[n];
    #pragma unroll
    for (int l = 0; l < LBL; ++l) {
        float q = v[l] * inv;
        A[l * NPIX + n] = ns * q;
        Qt0[qtidx(n, l)] = f2bf(nb * q);
    }
    #pragma unroll
    for (int l = LBL; l < LPAD; ++l) {
        Qt0[qtidx(n, l)] = 0;
        Qt1[qtidx(n, l)] = 0;
    }
}

// ---------------------------------------------------------------- k_sp (slow path)
__global__ void k_sp(const float* __restrict__ A, const float* __restrict__ nsp,
                     const float* __restrict__ U, float* __restrict__ SP) {
    __shared__ float ty[4 * WW];
    int l = blockIdx.x / 24;
    int y0 = (blockIdx.x % 24) * 4;
    int t = threadIdx.x;
    const float* Al = A + (size_t)l * NPIX;
    #pragma unroll
    for (int c = 0; c < 2; ++c) {
        int p = t + c * 256;
        if (p < 4 * WW) {
            int yy = p / WW, x = p % WW;
            int y = y0 + yy;
            float s = 0.f;
            #pragma unroll
            for (int d = -RAD; d <= RAD; ++d) {
                int yd = y + d;
                if ((unsigned)yd < HH) s += GK[d + RAD] * Al[yd * WW + x];
            }
            ty[p] = s;
        }
    }
    __syncthreads();
    #pragma unroll
    for (int c = 0; c < 2; ++c) {
        int p = t + c * 256;
        if (p < 4 * WW) {
            int yy = p / WW, x = p % WW;
            float s = 0.f;
            #pragma unroll
            for (int d = -RAD; d <= RAD; ++d) {
                int xd = x + d;
                if ((unsigned)xd < WW) s += GK[d + RAD] * ty[yy * WW + xd];
            }
            int pp = (y0 + yy) * WW + x;
            SP[(size_t)l * NPIX + pp] = POS_W_C * nsp[pp] * s - U[(size_t)l * NPIX + pp];
        }
    }
}

// ---------------------------------------------------------------- k_bi_fast
// grid = NITB*JCH = 2304, LDS-free GEMM (round-8 shape). Blocks 0..503 first
// run one spatial-conv band. Each wave: 16 i-rows, 18 jt tiles; A (K) and
// B (Qt) both MFMA-swizzled -> contiguous 1KB wave loads. Partials in bf16.
__global__ void __launch_bounds__(256, 8)
k_bi_fast(const unsigned short* __restrict__ K, const unsigned short* __restrict__ Qt,
          const float* __restrict__ A, const float* __restrict__ nsp,
          const float* __restrict__ U, float* __restrict__ SP,
          unsigned short* __restrict__ P) {
    int tid = threadIdx.x;
    int bid = blockIdx.x;

    // ---- fused spatial conv band (blocks 0..503)
    __shared__ float ty[4 * WW];
    if (bid < NSPB) {
        int l = bid / 24;
        int y0b = (bid % 24) * 4;
        const float* Al = A + (size_t)l * NPIX;
        #pragma unroll
        for (int c = 0; c < 2; ++c) {
            int p = tid + c * 256;
            if (p < 4 * WW) {
                int yy = p / WW, x = p % WW;
                int y = y0b + yy;
                float s = 0.f;
                #pragma unroll
                for (int d = -RAD; d <= RAD; ++d) {
                    int yd = y + d;
                    if ((unsigned)yd < HH) s += GK[d + RAD] * Al[yd * WW + x];
                }
                ty[p] = s;
            }
        }
        __syncthreads();
        #pragma unroll
        for (int c = 0; c < 2; ++c) {
            int p = tid + c * 256;
            if (p < 4 * WW) {
                int yy = p / WW, x = p % WW;
                float s = 0.f;
                #pragma unroll
                for (int d = -RAD; d <= RAD; ++d) {
                    int xd = x + d;
                    if ((unsigned)xd < WW) s += GK[d + RAD] * ty[yy * WW + xd];
                }
                int pp = (y0b + yy) * WW + x;
                SP[(size_t)l * NPIX + pp] = POS_W_C * nsp[pp] * s - U[(size_t)l * NPIX + pp];
            }
        }
    }

    int jc  = bid / NITB;          // 0..15
    int itb = bid % NITB;          // 0..143
    int jtb = jc * (JC / 32);      // 18 jtiles per chunk

    int lane = tid & 63;
    int wv = tid >> 6;
    int m  = lane & 15;
    int kh = lane >> 4;
    int it = itb * 4 + wv;         // 16-row i-tile

    const bf16x8* pa  = (const bf16x8*)K  + ((size_t)it * JTOT + jtb) * 64 + lane;
    const bf16x8* pb0 = (const bf16x8*)Qt + (size_t)jtb * 64 + lane;
    const bf16x8* pb1 = (const bf16x8*)Qt + (size_t)(QHALF / 8) + (size_t)jtb * 64 + lane;

    f32x4 acc0 = {0.f,0.f,0.f,0.f}, acc1 = {0.f,0.f,0.f,0.f};

    #pragma unroll 6
    for (int jt = 0; jt < JC / 32; ++jt) {     // 18 iters
        bf16x8 a  = pa[jt * 64];
        bf16x8 b0 = pb0[jt * 64];
        bf16x8 b1 = pb1[jt * 64];
        acc0 = __builtin_amdgcn_mfma_f32_16x16x32_bf16(a, b0, acc0, 0, 0, 0);
        acc1 = __builtin_amdgcn_mfma_f32_16x16x32_bf16(a, b1, acc1, 0, 0, 0);
    }

    // partials (bf16); C/D layout col(label)=m, row=kh*4+r
    unsigned short* Pp = P + (size_t)jc * NPIX * PSTR;
    int i0 = it * 16 + kh * 4;
    #pragma unroll
    for (int r = 0; r < 4; ++r) {
        Pp[(size_t)(i0 + r) * PSTR + m] = f2bf(acc0[r]);
        if (m < 8) Pp[(size_t)(i0 + r) * PSTR + 16 + m] = f2bf(acc1[r]);
    }
}

// ---------------------------------------------------------------- k_red
// 288 blocks x 256: 8 groups each sum 2 j-chunks (bf16 partials, 3x16B loads
// per chunk); LDS reduce (stride-25 pad); wave-0 lanes do fused softmax
// epilogue + swizzled Qt writes.
__global__ void __launch_bounds__(256)
k_red(const unsigned short* __restrict__ P, const float* __restrict__ SP,
      const float* __restrict__ nbi, const float* __restrict__ nsp,
      float* __restrict__ Qo, float* __restrict__ Ao,
      unsigned short* __restrict__ Qto) {
    __shared__ float red[8][32][25];
    int tid = threadIdx.x;
    int p32 = tid & 31;
    int g = tid >> 5;
    int p = blockIdx.x * 32 + p32;

    float acc[24];
    #pragma unroll
    for (int l = 0; l < 24; ++l) acc[l] = 0.f;
    #pragma unroll
    for (int jj = 0; jj < 2; ++jj) {
        int jcc = g * 2 + jj;
        const uint4* pp = (const uint4*)(P + ((size_t)jcc * NPIX + p) * PSTR);
        #pragma unroll
        for (int q = 0; q < 3; ++q) {
            uint4 u = pp[q];
            acc[8*q+0] += bf2f((unsigned short)(u.x & 0xffff));
            acc[8*q+1] += bf2f((unsigned short)(u.x >> 16));
            acc[8*q+2] += bf2f((unsigned short)(u.y & 0xffff));
            acc[8*q+3] += bf2f((unsigned short)(u.y >> 16));
            acc[8*q+4] += bf2f((unsigned short)(u.z & 0xffff));
            acc[8*q+5] += bf2f((unsigned short)(u.z >> 16));
            acc[8*q+6] += bf2f((unsigned short)(u.w & 0xffff));
            acc[8*q+7] += bf2f((unsigned short)(u.w >> 16));
        }
    }
    #pragma unroll
    for (int l = 0; l < 24; ++l) red[g][p32][l] = acc[l];
    __syncthreads();
    if (tid >= 32) return;

    float nb = nbi[p];
    float ns = nsp[p];
    float v[LBL];
    float mx = -1e30f;
    #pragma unroll
    for (int l = 0; l < LBL; ++l) {
        float bi = 0.f;
        #pragma unroll
        for (int q = 0; q < 8; ++q) bi += red[q][p32][l];
        v[l] = SP[l * NPIX + p] + BI_W_C * nb * bi;
        mx = fmaxf(mx, v[l]);
    }
    float ssum = 0.f;
    #pragma unroll
    for (int l = 0; l < LBL; ++l) { v[l] = __expf(v[l] - mx); ssum += v[l]; }
    float inv = 1.f / ssum;
    #pragma unroll
    for (int l = 0; l < LBL; ++l) {
        float q = v[l] * inv;
        Qo[l * NPIX + p] = q;
        Ao[l * NPIX + p] = ns * q;
        Qto[qtidx(p, l)] = f2bf(nb * q);
    }
}

// ---------------------------------------------------------------- k_bi_slow
__global__ void k_bi_slow(const float* __restrict__ fx, const float* __restrict__ fy,
                          const float* __restrict__ fr, const float* __restrict__ fg,
                          const float* __restrict__ fb,
                          const float* __restrict__ nbi, const unsigned short* __restrict__ Qt,
                          const float* __restrict__ SP, const float* __restrict__ nsp,
                          float* __restrict__ Qo, float* __restrict__ Ao,
                          unsigned short* __restrict__ Qto) {
    int t = threadIdx.x;
    int px = t & 15, st = t >> 4;
    int i = blockIdx.x * 16 + px;
    float xi = fx[i], yi = fy[i], ri = fr[i], gi = fg[i], bi = fb[i];
    float acc[LBL];
    #pragma unroll
    for (int l = 0; l < LBL; ++l) acc[l] = 0.f;
    int j0 = st * (NPIX / 16);
    for (int j = j0; j < j0 + NPIX / 16; ++j) {
        float dx = xi - fx[j], dy = yi - fy[j];
        float dr = ri - fr[j], dg = gi - fg[j], db = bi - fb[j];
        float D = dx*dx + dy*dy + dr*dr + dg*dg + db*db;
        float w = __expf(-0.5f * D);
        #pragma unroll
        for (int l = 0; l < LBL; ++l) acc[l] += w * bf2f(Qt[qtidx(j, l)]);
    }
    __shared__ float red[16][LBL];
    if (st == 0) {
        #pragma unroll
        for (int l = 0; l < LBL; ++l) red[px][l] = acc[l];
    }
    __syncthreads();
    for (int s = 1; s < 16; ++s) {
        if (st == s) {
            #pragma unroll
            for (int l = 0; l < LBL; ++l) red[px][l] += acc[l];
        }
        __syncthreads();
    }
    if (t < 16) {
        int i2 = blockIdx.x * 16 + t;
        float nb = nbi[i2];
        float ns = nsp[i2];
        float v[LBL];
        float mx = -1e30f;
        #pragma unroll
        for (int l = 0; l < LBL; ++l) {
            v[l] = SP[l * NPIX + i2] + BI_W_C * nb * red[t][l];
            mx = fmaxf(mx, v[l]);
        }
        float s = 0.f;
        #pragma unroll
        for (int l = 0; l < LBL; ++l) { v[l] = __expf(v[l] - mx); s += v[l]; }
        float inv = 1.f / s;
        #pragma unroll
        for (int l = 0; l < LBL; ++l) {
            float q = v[l] * inv;
            Qo[l * NPIX + i2] = q;
            Ao[l * NPIX + i2] = ns * q;
            Qto[qtidx(i2, l)] = f2bf(nb * q);
        }
    }
}

// ---------------------------------------------------------------- launch
extern "C" void kernel_launch(void* const* d_in, const int* in_sizes, int n_in,
                              void* d_out, int out_size, void* d_ws, size_t ws_size,
                              hipStream_t stream) {
    const float* U = (const float*)d_in[0];
    const float* I = (const float*)d_in[1];

    char* w = (char*)d_ws;
    float* fx  = (float*)w;                 w += NPIX * sizeof(float);
    float* fy  = (float*)w;                 w += NPIX * sizeof(float);
    float* fr  = (float*)w;                 w += NPIX * sizeof(float);
    float* fg  = (float*)w;                 w += NPIX * sizeof(float);
    float* fb  = (float*)w;                 w += NPIX * sizeof(float);
    float* S   = (float*)w;                 w += NPIX * sizeof(float);
    float* nsp = (float*)w;                 w += NPIX * sizeof(float);
    float* nbi = (float*)w;                 w += NPIX * sizeof(float);
    float* RS  = (float*)w;                 w += (size_t)KSPLIT * NPIX * sizeof(float);
    float* A   = (float*)w;                 w += (size_t)LBL * NPIX * sizeof(float);
    float* SP  = (float*)w;                 w += (size_t)LBL * NPIX * sizeof(float);
    unsigned short* Qtb[2];
    Qtb[0] = (unsigned short*)w;            w += (size_t)2 * QHALF * sizeof(unsigned short);
    Qtb[1] = (unsigned short*)w;            w += (size_t)2 * QHALF * sizeof(unsigned short);
    unsigned short* P = (unsigned short*)w; w += (size_t)JCH * NPIX * PSTR * sizeof(unsigned short);
    unsigned short* K = (unsigned short*)w;
    size_t need = (size_t)(w - (char*)d_ws) + (size_t)NPIX * NPIX * sizeof(unsigned short);
    bool fast = (ws_size >= need);

    float* Qout = (float*)d_out;

    k_prep<<<(NPIX + 255) / 256, 256, 0, stream>>>(I, fx, fy, fr, fg, fb, S, nsp);
    if (fast) k_K<true ><<<(NPIX / 16) * KSPLIT, 256, 0, stream>>>(fx, fy, fr, fg, fb, S, RS, K);
    else      k_K<false><<<(NPIX / 16) * KSPLIT, 256, 0, stream>>>(fx, fy, fr, fg, fb, S, RS, nullptr);
    k_q0<<<(NPIX + 255) / 256, 256, 0, stream>>>(U, RS, nsp, nbi, A, Qtb[0], Qtb[1]);

    for (int t = 0; t < N_ITER; ++t) {
        const unsigned short* Qtin = Qtb[t & 1];
        unsigned short* Qtout = Qtb[(t + 1) & 1];
        if (fast) {
            k_bi_fast<<<NITB * JCH, 256, 0, stream>>>(K, Qtin, A, nsp, U, SP, P);
            k_red<<<NPIX / 32, 256, 0, stream>>>(P, SP, nbi, nsp, Qout, A, Qtout);
        } else {
            k_sp<<<NSPB, 256, 0, stream>>>(A, nsp, U, SP);
            k_bi_slow<<<NPIX / 16, 256, 0, stream>>>(fx, fy, fr, fg, fb, nbi, Qtin, SP, nsp, Qout, A, Qtout);
        }
    }
}